// Round 7
// baseline (377.464 us; speedup 1.0000x reference)
//
#include <hip/hip_runtime.h>
#include <math.h>

#define ANUM 3
#define CNUM 3
#define BNUM 32
#define MNUM 16
#define CH 24      // ANUM*(5+CNUM)
#define NBIN 4096  // 12-bit float-top-bits histogram (sign=0 for all values)
#define NSEG 96
#define CAP 8192   // max in-threshold-bin candidates kept
#define CHUNK 4800 // elements per chunk; divides 76800/19200/4800
#define CPB 21     // chunks per batch image: 16 + 4 + 1

// All small state in static device memory -> workspace holds ONLY negvals.
__device__ __align__(16) int   g_hist[NSEG*NBIN];
__device__ __align__(16) float g_cand[(size_t)NSEG*CAP];
__device__ int   g_ccnt[NSEG];
__device__ int   g_T[NSEG];
__device__ int   g_kk[NSEG];
__device__ int   g_cab[NSEG];   // count strictly above bin T
__device__ float g_sab[NSEG];   // sum of values strictly above bin T
__device__ float g_acc[NSEG*5];
__device__ float g_lsum[3];
__device__ int   g_arr1[NSEG];  // k1 per-segment arrival
__device__ int   g_arr2[NSEG];  // scan per-segment arrival
__device__ int   g_done;

__device__ __forceinline__ float wred(float v){
  #pragma unroll
  for (int off=32; off; off>>=1) v += __shfl_down(v, off, 64);
  return v;
}
__device__ __forceinline__ int wredi(int v){
  #pragma unroll
  for (int off=32; off; off>>=1) v += __shfl_down(v, off, 64);
  return v;
}

__device__ __forceinline__ void seg_map(int c, int& s, int& ci){
  if (c < 16){ s = 0; ci = c; }
  else if (c < 20){ s = 1; ci = c - 16; }
  else { s = 2; ci = 0; }
}
__device__ __forceinline__ void seg_geom(int s, int& N, size_t& segbase){
  N = (s==0) ? 76800 : ((s==1) ? 19200 : 4800);
  segbase = (s==0) ? 0
          : ((s==1) ? (size_t)BNUM*76800
                    : (size_t)BNUM*(76800+19200));
}

__global__ __launch_bounds__(256) void kinit(){
  const int gid = blockIdx.x*256 + threadIdx.x;   // 384*256 = 98304
  ((int4*)g_hist)[gid] = make_int4(0,0,0,0);      // 98304*4 = NSEG*NBIN
  if (gid < NSEG*5) g_acc[gid] = 0.f;
  if (gid < 3) g_lsum[gid] = 0.f;
  if (gid == 3) g_done = 0;
  if (gid < NSEG){ g_ccnt[gid]=0; g_sab[gid]=0.f; g_arr1[gid]=0; g_arr2[gid]=0; }
}

// One thread per PIXEL: 3 anchors in registers, shared box corners,
// divide-free argmax (cross-multiplication), one divide per anchor at end
// (same operands/order as reference -> bit-identical best/thresholds).
template<int H, int W, int SCALE>
__device__ __forceinline__ void k1_work(
    const float* __restrict__ pred, float* __restrict__ negvals,
    const float* sbox, const int* slab, int b, int pix, int* lh, float* f)
{
  constexpr int HW = H*W;
  constexpr int N = HW*ANUM;
  constexpr size_t segbase = (SCALE==0) ? 0
                           : ((SCALE==1) ? (size_t)BNUM*76800
                                         : (size_t)BNUM*(76800+19200));
  const bool valid = (pix < HW);
  const int pp = valid ? pix : 0;
  const int h = pp / W, w = pp % W;
  const float cx = ((float)w + 0.5f)/(float)W;
  const float cy = ((float)h + 0.5f)/(float)H;

  const float* pb = pred + (size_t)b*CH*HW;
  float obj[3];
  #pragma unroll
  for (int a=0;a<3;a++) obj[a] = pb[(a*8+4)*HW + pp];   // coalesced

  float ax0[3],ay0[3],ax1[3],ay1[3],areaA[3];
  #pragma unroll
  for (int a=0;a<3;a++){
    const float sz=(a==0)?0.08f:((a==1)?0.16f:0.28f);
    const float hs=sz*0.5f;
    ax0[a]=cx-hs; ay0[a]=cy-hs; ax1[a]=cx+hs; ay1[a]=cy+hs;
    areaA[a]=(ax1[a]-ax0[a])*(ay1[a]-ay0[a]);
  }
  float bi[3]={-1.f,-1.f,-1.f}, bu[3]={1.f,1.f,1.f};
  int bm[3]={0,0,0};
  #pragma unroll
  for (int m=0;m<MNUM;m++){
    const float bcx=sbox[4*m], bcy=sbox[4*m+1], bw=sbox[4*m+2], bh=sbox[4*m+3];
    const float bx0=bcx-bw*0.5f, by0=bcy-bh*0.5f, bx1=bcx+bw*0.5f, by1=bcy+bh*0.5f;
    const float areaB=(bx1-bx0)*(by1-by0);
    #pragma unroll
    for (int a=0;a<3;a++){
      float iw=fminf(ax1[a],bx1)-fmaxf(ax0[a],bx0);
      float ih=fminf(ay1[a],by1)-fmaxf(ay0[a],by0);
      iw=fmaxf(iw,0.f); ih=fmaxf(ih,0.f);
      const float inter=iw*ih;
      const float uni=areaA[a]+areaB-inter+1e-9f;
      // iou_new > iou_best  <=>  inter*bu > bi*uni   (uni,bu > 0)
      if (inter*bu[a] > bi[a]*uni){ bi[a]=inter; bu[a]=uni; bm[a]=m; }
    }
  }
  #pragma unroll
  for (int a=0;a<3;a++){
    const float best = bi[a]/bu[a];       // same operands as reference iou
    const bool pos = best >= 0.5f;
    const bool neg = best < 0.4f;
    const float o = obj[a];
    const float sp = log1pf(expf(-fabsf(o)));
    const float obj_all = fmaxf(o,0.f) - (pos? o:0.f) + sp;
    if (valid){
      negvals[segbase + (size_t)b*N + pp*3 + a] = neg ? obj_all : -1.f;
      if (neg){
        atomicAdd(&lh[__float_as_uint(obj_all)>>20], 1);
        f[1] += 1.f;
      }
      if (pos){
        f[0]+=1.f; f[2]+=obj_all;
        const int midx=bm[a];
        int ct = slab[midx]-1; ct = ct<0?0:(ct>CNUM-1?CNUM-1:ct);
        const int cb=a*8;
        float c0=pb[(cb+5)*HW+pp], c1=pb[(cb+6)*HW+pp], c2=pb[(cb+7)*HW+pp];
        float mx=fmaxf(c0,fmaxf(c1,c2));
        float lse=mx+logf(expf(c0-mx)+expf(c1-mx)+expf(c2-mx));
        float csel=(ct==0)?c0:((ct==1)?c1:c2);
        f[3]+=lse-csel;
        const float sz=(a==0)?0.08f:((a==1)?0.16f:0.28f);
        float mcx=sbox[4*midx],mcy=sbox[4*midx+1],mw=sbox[4*midx+2],mh=sbox[4*midx+3];
        float t0=(mcx-cx)/sz,t1=(mcy-cy)/sz,t2=logf(mw/sz),t3=logf(mh/sz);
        float l0=pb[(cb+0)*HW+pp],l1=pb[(cb+1)*HW+pp],l2=pb[(cb+2)*HW+pp],l3=pb[(cb+3)*HW+pp];
        float ssum=0.f,d;
        d=fabsf(l0-t0); ssum+=(d<1.f)?(0.5f*d*d):(d-0.5f);
        d=fabsf(l1-t1); ssum+=(d<1.f)?(0.5f*d*d):(d-0.5f);
        d=fabsf(l2-t2); ssum+=(d<1.f)?(0.5f*d*d):(d-0.5f);
        d=fabsf(l3-t3); ssum+=(d<1.f)?(0.5f*d*d):(d-0.5f);
        f[4]+=ssum;
      }
    }
  }
}

// Merged over all 3 scales; LDS-private histogram fused; last block per
// segment (arrival counter) computes the radix pick (T, kk, cab).
__global__ __launch_bounds__(256) void k1_all(
    const float* __restrict__ pred0, const float* __restrict__ pred1,
    const float* __restrict__ pred2, const float* __restrict__ boxes,
    const int* __restrict__ labels, float* __restrict__ negvals)
{
  __shared__ float sbox[MNUM*4];
  __shared__ int   slab[MNUM];
  __shared__ int   lh[NBIN];          // 16 KB (reused as global-hist copy in pick)
  __shared__ float red[5][4];

  const int b = blockIdx.y;
  if (threadIdx.x < MNUM*4) sbox[threadIdx.x] = boxes[b*MNUM*4 + threadIdx.x];
  else if (threadIdx.x < MNUM*5) slab[threadIdx.x - MNUM*4] = labels[b*MNUM + (threadIdx.x - MNUM*4)];
  int4* lh4 = (int4*)lh;
  for (int i=threadIdx.x; i<NBIN/4; i+=256) lh4[i] = make_int4(0,0,0,0);
  __syncthreads();

  const int c = blockIdx.x;   // 0..131 : 100 s0 + 25 s1 + 7 s2
  float f[5] = {0.f,0.f,0.f,0.f,0.f};
  int g, nblk;
  if (c < 100){ g = b; nblk = 100;
    k1_work<160,160,0>(pred0, negvals, sbox, slab, b, c*256 + (int)threadIdx.x, lh, f); }
  else if (c < 125){ g = BNUM + b; nblk = 25;
    k1_work<80,80,1>(pred1, negvals, sbox, slab, b, (c-100)*256 + (int)threadIdx.x, lh, f); }
  else { g = 2*BNUM + b; nblk = 7;
    k1_work<40,40,2>(pred2, negvals, sbox, slab, b, (c-125)*256 + (int)threadIdx.x, lh, f); }

  const int lane = threadIdx.x & 63, wv = threadIdx.x >> 6;
  #pragma unroll
  for (int q=0;q<5;q++){
    float r = wred(f[q]);
    if (lane==0) red[q][wv] = r;
  }
  __syncthreads();
  if (threadIdx.x < 5){
    const int q = threadIdx.x;
    float t = red[q][0]+red[q][1]+red[q][2]+red[q][3];
    if (t != 0.f) atomicAdd(&g_acc[g*5+q], t);
  }
  int* gh = g_hist + (size_t)g*NBIN;
  for (int i=threadIdx.x; i<NBIN/4; i+=256){
    int4 hv = lh4[i];
    if (hv.x) atomicAdd(gh + i*4 + 0, hv.x);
    if (hv.y) atomicAdd(gh + i*4 + 1, hv.y);
    if (hv.z) atomicAdd(gh + i*4 + 2, hv.z);
    if (hv.w) atomicAdd(gh + i*4 + 3, hv.w);
  }
  __syncthreads();   // all flush atomics issued+acked before arrival

  // ---- arrival; last block per segment runs the pick ----
  __shared__ int s_lastb;
  if (threadIdx.x==0){
    int prev = __hip_atomic_fetch_add(&g_arr1[g], 1, __ATOMIC_ACQ_REL, __HIP_MEMORY_SCOPE_AGENT);
    s_lastb = (prev == nblk-1) ? 1 : 0;
  }
  __syncthreads();
  if (!s_lastb) return;

  // Reload full per-segment hist (coherence-point reads) into lh.
  for (int i=threadIdx.x; i<NBIN; i+=256)
    lh[i] = __hip_atomic_load(gh + i, __ATOMIC_RELAXED, __HIP_MEMORY_SCOPE_AGENT);
  __shared__ float s_np, s_av;
  if (threadIdx.x==0){
    s_np = __hip_atomic_load(&g_acc[g*5+0], __ATOMIC_RELAXED, __HIP_MEMORY_SCOPE_AGENT);
    s_av = __hip_atomic_load(&g_acc[g*5+1], __ATOMIC_RELAXED, __HIP_MEMORY_SCOPE_AGENT);
  }
  __syncthreads();

  const int npos = (int)(s_np + 0.5f);
  const int avail = (int)(s_av + 0.5f);
  const int k = (npos==0) ? (avail < 100 ? avail : 100)
                          : (3*npos < avail ? 3*npos : avail);

  __shared__ int tsum[256];
  __shared__ int s_tt, s_cum;
  int ssum2 = 0;
  #pragma unroll
  for (int i=0;i<16;i++) ssum2 += lh[threadIdx.x*16 + i];
  tsum[threadIdx.x] = ssum2;
  __syncthreads();

  if (k > 0){
    if (threadIdx.x==0){
      int cum=0, tt=0;
      for (int t=255;t>=0;t--){
        if (cum + tsum[t] >= k){ tt=t; break; }
        cum += tsum[t];
      }
      s_tt = tt; s_cum = cum;
    }
    __syncthreads();
    if (threadIdx.x == s_tt){
      int cum = s_cum, T=0, kk=0;
      for (int j=15;j>=0;j--){
        int cc = lh[s_tt*16 + j];
        if (cum + cc >= k){ T = s_tt*16 + j; kk = k - cum; break; }
        cum += cc;
      }
      g_T[g]=T; g_kk[g]=kk; g_cab[g]=cum;
    }
  } else if (threadIdx.x==0){
    g_T[g]=0x7FFFFFFF; g_kk[g]=0; g_cab[g]=0;
  }
}

// Full-width scan (sum above-bin, compact in-bin candidates) fused with the
// per-segment refinement: last-arriving block per segment runs the 3-pass
// radix over candidates + final loss; very last segment writes out[].
__global__ __launch_bounds__(256) void k2_scanfin(
    const float* __restrict__ negvals, float* __restrict__ out)
{
  const int bid = blockIdx.x;            // 672 blocks
  const int b = bid / CPB;
  int s, ci; seg_map(bid % CPB, s, ci);
  const int g = s*BNUM + b;
  int N; size_t segbase; seg_geom(s, N, segbase);
  const float* segc = negvals + segbase + (size_t)b*N + (size_t)ci*CHUNK;
  const int T = g_T[g];
  const int lane = threadIdx.x & 63;
  const int nblk = (s==0) ? 16 : ((s==1) ? 4 : 1);

  __shared__ float cv[CAP];              // 32 KB (fin phase)
  __shared__ int hist[256];
  __shared__ int s_bin, s_rem, s_lastb;
  __shared__ float redf[4];
  __shared__ int   redi[4];
  __shared__ int   s_base, s_loc;
  __shared__ float red2[2][4];

  const float4* p4 = (const float4*)segc;
  float sab = 0.f; int cnt = 0;

  // Pass A: count in-bin, sum above-bin.
  for (int i = threadIdx.x; i < CHUNK/4; i += 256){
    float4 v4 = p4[i];
    #pragma unroll
    for (int j=0;j<4;j++){
      float v = (&v4.x)[j];
      if (v < 0.f) continue;
      const int bin = (int)(__float_as_uint(v) >> 20);
      if (bin > T) sab += v;
      else if (bin == T) cnt++;
    }
  }

  float r = wred(sab); int c2 = wredi(cnt);
  if (lane == 0){ redf[threadIdx.x>>6] = r; redi[threadIdx.x>>6] = c2; }
  __syncthreads();
  if (threadIdx.x == 0){
    float t = redf[0]+redf[1]+redf[2]+redf[3];
    int   n = redi[0]+redi[1]+redi[2]+redi[3];
    if (t != 0.f) atomicAdd(&g_sab[g], t);
    s_base = (n > 0) ? atomicAdd(&g_ccnt[g], n) : 0;
    s_loc = 0;
  }
  __syncthreads();
  const int base = s_base;
  const bool anyT = (__syncthreads_count(cnt > 0) != 0);

  // Pass B: compact in-bin values (chunk is cache-hot; order irrelevant).
  if (anyT){
    for (int i = threadIdx.x; i < CHUNK/4; i += 256){
      float4 v4 = p4[i];
      #pragma unroll
      for (int j=0;j<4;j++){
        float v = (&v4.x)[j];
        const bool isT = (v >= 0.f) && ((int)(__float_as_uint(v) >> 20) == T);
        unsigned long long peers = __ballot(isT ? 1 : 0);
        if (isT){
          const int leader = __ffsll(peers) - 1;
          int wbase = 0;
          if (lane == leader) wbase = atomicAdd(&s_loc, (int)__popcll(peers));
          wbase = __shfl(wbase, leader, 64);
          const int idx = base + wbase + (int)__popcll(peers & ((1ull<<lane)-1ull));
          if (idx < CAP)
            __hip_atomic_store(&g_cand[(size_t)g*CAP + idx], v,
                               __ATOMIC_RELAXED, __HIP_MEMORY_SCOPE_AGENT);
        }
      }
    }
  }
  __syncthreads();   // all stores/atomics issued+acked before arrival

  // ---- arrival; last block per segment runs the refinement + loss ----
  if (threadIdx.x==0){
    int prev = __hip_atomic_fetch_add(&g_arr2[g], 1, __ATOMIC_ACQ_REL, __HIP_MEMORY_SCOPE_AGENT);
    s_lastb = (prev == nblk-1) ? 1 : 0;
  }
  __syncthreads();
  if (!s_lastb) return;

  const float* seg = negvals + segbase + (size_t)b*N;   // full segment
  __shared__ float s_np, s_av, s_sab;
  __shared__ int s_C;
  if (threadIdx.x==0){
    s_np  = __hip_atomic_load(&g_acc[g*5+0], __ATOMIC_RELAXED, __HIP_MEMORY_SCOPE_AGENT);
    s_av  = __hip_atomic_load(&g_acc[g*5+1], __ATOMIC_RELAXED, __HIP_MEMORY_SCOPE_AGENT);
    s_sab = __hip_atomic_load(&g_sab[g],     __ATOMIC_RELAXED, __HIP_MEMORY_SCOPE_AGENT);
    s_C   = __hip_atomic_load(&g_ccnt[g],    __ATOMIC_RELAXED, __HIP_MEMORY_SCOPE_AGENT);
  }
  __syncthreads();

  const float npos_f = s_np;
  const int npos = (int)(npos_f + 0.5f);
  const int avail = (int)(s_av + 0.5f);
  const int k = (npos==0) ? (avail < 100 ? avail : 100)
                          : (3*npos < avail ? 3*npos : avail);

  float ss = 0.f, ns = 0.f;
  float sab2 = 0.f, cab_f = 0.f;

  if (k > 0){
    const int kk0 = g_kk[g];
    const int cab = g_cab[g];
    sab2 = s_sab;
    cab_f = (float)cab;
    const int C = s_C;

    unsigned prel = 0, pm = 0;
    int rem = kk0;

    if (C <= CAP){
      for (int i=threadIdx.x; i<C; i+=256)
        cv[i] = __hip_atomic_load(&g_cand[(size_t)g*CAP + i],
                                  __ATOMIC_RELAXED, __HIP_MEMORY_SCOPE_AGENT);
      __syncthreads();
      #pragma unroll
      for (int p=0;p<3;p++){
        const int shift = (p==0)?12:((p==1)?4:0);
        const unsigned bmax = (p==2)?15u:255u;
        hist[threadIdx.x] = 0;
        __syncthreads();
        for (int i=threadIdx.x; i<C; i+=256){
          unsigned u20 = __float_as_uint(cv[i]) & 0xFFFFFu;
          if ((u20 & pm) == prel) atomicAdd(&hist[(u20>>shift)&bmax], 1);
        }
        __syncthreads();
        if (threadIdx.x==0){
          int cum=0;
          for (int j=(int)bmax;j>=0;j--){
            cum += hist[j];
            if (cum >= rem){ s_bin=j; s_rem = rem-(cum-hist[j]); break; }
          }
        }
        __syncthreads();
        prel |= ((unsigned)s_bin << shift);
        pm |= (bmax << shift);
        rem = s_rem;
        __syncthreads();
      }
      const float thr = __uint_as_float(((unsigned)T << 20) | prel);
      for (int i=threadIdx.x; i<C; i+=256){
        float v = cv[i];
        if (v >= thr){ ss += v; ns += 1.f; }
      }
    } else {
      // Overflow fallback: radix over the full segment from global.
      const float4* q4 = (const float4*)seg;
      const int N4 = N >> 2;
      #pragma unroll
      for (int p=0;p<3;p++){
        const int shift = (p==0)?12:((p==1)?4:0);
        const unsigned bmax = (p==2)?15u:255u;
        hist[threadIdx.x] = 0;
        __syncthreads();
        for (int i=threadIdx.x; i<N4; i+=256){
          float4 v4 = q4[i];
          #pragma unroll
          for (int j=0;j<4;j++){
            float v = (&v4.x)[j];
            if (v < 0.f) continue;
            unsigned u = __float_as_uint(v);
            if ((int)(u >> 20) != T) continue;
            unsigned u20 = u & 0xFFFFFu;
            if ((u20 & pm) == prel) atomicAdd(&hist[(u20>>shift)&bmax], 1);
          }
        }
        __syncthreads();
        if (threadIdx.x==0){
          int cum=0;
          for (int j=(int)bmax;j>=0;j--){
            cum += hist[j];
            if (cum >= rem){ s_bin=j; s_rem = rem-(cum-hist[j]); break; }
          }
        }
        __syncthreads();
        prel |= ((unsigned)s_bin << shift);
        pm |= (bmax << shift);
        rem = s_rem;
        __syncthreads();
      }
      const float thr = __uint_as_float(((unsigned)T << 20) | prel);
      for (int i=threadIdx.x; i<N4; i+=256){
        float4 v4 = q4[i];
        #pragma unroll
        for (int j=0;j<4;j++){
          float v = (&v4.x)[j];
          if (v < 0.f) continue;
          if ((int)(__float_as_uint(v) >> 20) == T && v >= thr){ ss += v; ns += 1.f; }
        }
      }
    }
  }

  const int wv = threadIdx.x >> 6;
  float r0 = wred(ss), r1 = wred(ns);
  if (lane==0){ red2[0][wv]=r0; red2[1][wv]=r1; }
  __syncthreads();
  if (threadIdx.x==0){
    float sstot = sab2 + red2[0][0]+red2[0][1]+red2[0][2]+red2[0][3];
    float nstot = cab_f + red2[1][0]+red2[1][1]+red2[1][2]+red2[1][3];
    float cnt2 = npos_f + nstot;
    float ag2 = __hip_atomic_load(&g_acc[g*5+2], __ATOMIC_RELAXED, __HIP_MEMORY_SCOPE_AGENT);
    float ag3 = __hip_atomic_load(&g_acc[g*5+3], __ATOMIC_RELAXED, __HIP_MEMORY_SCOPE_AGENT);
    float ag4 = __hip_atomic_load(&g_acc[g*5+4], __ATOMIC_RELAXED, __HIP_MEMORY_SCOPE_AGENT);
    float lo = (cnt2 > 0.f) ? (ag2 + sstot)/cnt2 : 0.f;
    float lc = (npos > 0) ? ag3/npos_f : 0.f;
    float ll = (npos > 0) ? ag4/(npos_f*4.f) : 0.f;
    atomicAdd(&g_lsum[0], lo);
    atomicAdd(&g_lsum[1], lc);
    atomicAdd(&g_lsum[2], ll);
    __threadfence();
    if (__hip_atomic_fetch_add(&g_done, 1, __ATOMIC_ACQ_REL, __HIP_MEMORY_SCOPE_AGENT) == NSEG-1){
      float L0 = __hip_atomic_load(&g_lsum[0], __ATOMIC_RELAXED, __HIP_MEMORY_SCOPE_AGENT);
      float L1 = __hip_atomic_load(&g_lsum[1], __ATOMIC_RELAXED, __HIP_MEMORY_SCOPE_AGENT);
      float L2 = __hip_atomic_load(&g_lsum[2], __ATOMIC_RELAXED, __HIP_MEMORY_SCOPE_AGENT);
      float lo2 = L0*(1.f/32.f), lc2 = L1*(1.f/32.f), ll2 = L2*(1.f/32.f);
      out[0]=lo2; out[1]=lc2; out[2]=ll2; out[3]=lo2+lc2+ll2;
    }
  }
}

extern "C" void kernel_launch(void* const* d_in, const int* in_sizes, int n_in,
                              void* d_out, int out_size, void* d_ws, size_t ws_size,
                              hipStream_t stream)
{
  const float* pred0 = (const float*)d_in[0];
  const float* pred1 = (const float*)d_in[1];
  const float* pred2 = (const float*)d_in[2];
  const float* boxes = (const float*)d_in[6];
  const int*   labels = (const int*)d_in[7];
  float* out = (float*)d_out;

  float* negvals = (float*)d_ws;   // 3,225,600 floats = 12.9 MB (only ws use)

  kinit<<<384, 256, 0, stream>>>();
  k1_all<<<dim3(132,32), 256, 0, stream>>>(pred0, pred1, pred2, boxes, labels, negvals);
  k2_scanfin<<<672, 256, 0, stream>>>(negvals, out);
}

// Round 8
// 240.784 us; speedup vs baseline: 1.5676x; 1.5676x over previous
//
#include <hip/hip_runtime.h>
#include <math.h>

#define ANUM 3
#define CNUM 3
#define BNUM 32
#define MNUM 16
#define CH 24      // ANUM*(5+CNUM)
#define NBIN 4096  // 12-bit float-top-bits histogram (sign=0 for all values)
#define NSEG 96
#define CAP 8192   // max in-threshold-bin candidates kept
#define CHUNK 4800 // elements per chunk; divides 76800/19200/4800
#define CPB 21     // chunks per batch image: 16 + 4 + 1

// All small state in static device memory (zero-initialized at load).
// Each iteration self-cleans -> no init kernel needed.
__device__ __align__(16) int   g_hist[NSEG*NBIN];
__device__ __align__(16) float g_cand[(size_t)NSEG*CAP];
__device__ int   g_ccnt[NSEG];
__device__ int   g_T[NSEG];
__device__ int   g_kk[NSEG];
__device__ int   g_cab[NSEG];   // count strictly above bin T
__device__ float g_sab[NSEG];   // sum of values strictly above bin T
__device__ float g_acc[NSEG*5];
__device__ float g_lsum[3];
__device__ int   g_arr1[NSEG];  // k1 per-segment arrival
__device__ int   g_arr2[NSEG];  // scan per-segment arrival
__device__ int   g_done;

__device__ __forceinline__ float wred(float v){
  #pragma unroll
  for (int off=32; off; off>>=1) v += __shfl_down(v, off, 64);
  return v;
}
__device__ __forceinline__ int wredi(int v){
  #pragma unroll
  for (int off=32; off; off>>=1) v += __shfl_down(v, off, 64);
  return v;
}

// Relaxed agent-scope arrival. Prior atomics from this block are already
// acked (syncthreads drains vmcnt); relaxed RMW adds NO L2 writeback/inv
// (the acq_rel version cost ~4000 wbl2+inv ops = 3.5x slowdown, r7).
__device__ __forceinline__ int arrive(int* ctr){
  asm volatile("s_waitcnt vmcnt(0)" ::: "memory");
  return __hip_atomic_fetch_add(ctr, 1, __ATOMIC_RELAXED, __HIP_MEMORY_SCOPE_AGENT);
}
__device__ __forceinline__ int aload_i(const int* p){
  return __hip_atomic_load(p, __ATOMIC_RELAXED, __HIP_MEMORY_SCOPE_AGENT);
}
__device__ __forceinline__ float aload_f(const float* p){
  return __hip_atomic_load(p, __ATOMIC_RELAXED, __HIP_MEMORY_SCOPE_AGENT);
}

__device__ __forceinline__ void seg_map(int c, int& s, int& ci){
  if (c < 16){ s = 0; ci = c; }
  else if (c < 20){ s = 1; ci = c - 16; }
  else { s = 2; ci = 0; }
}
__device__ __forceinline__ void seg_geom(int s, int& N, size_t& segbase){
  N = (s==0) ? 76800 : ((s==1) ? 19200 : 4800);
  segbase = (s==0) ? 0
          : ((s==1) ? (size_t)BNUM*76800
                    : (size_t)BNUM*(76800+19200));
}

// One thread per PIXEL: 3 anchors in registers, shared box corners,
// divide-free argmax (cross-multiplication), one divide per anchor at end
// (same operands/order as reference -> bit-identical best/thresholds).
template<int H, int W, int SCALE>
__device__ __forceinline__ void k1_work(
    const float* __restrict__ pred, float* __restrict__ negvals,
    const float* sbox, const int* slab, int b, int pix, int* lh, float* f)
{
  constexpr int HW = H*W;
  constexpr int N = HW*ANUM;
  constexpr size_t segbase = (SCALE==0) ? 0
                           : ((SCALE==1) ? (size_t)BNUM*76800
                                         : (size_t)BNUM*(76800+19200));
  const bool valid = (pix < HW);
  const int pp = valid ? pix : 0;
  const int h = pp / W, w = pp % W;
  const float cx = ((float)w + 0.5f)/(float)W;
  const float cy = ((float)h + 0.5f)/(float)H;

  const float* pb = pred + (size_t)b*CH*HW;
  float obj[3];
  #pragma unroll
  for (int a=0;a<3;a++) obj[a] = pb[(a*8+4)*HW + pp];   // coalesced

  float ax0[3],ay0[3],ax1[3],ay1[3],areaA[3];
  #pragma unroll
  for (int a=0;a<3;a++){
    const float sz=(a==0)?0.08f:((a==1)?0.16f:0.28f);
    const float hs=sz*0.5f;
    ax0[a]=cx-hs; ay0[a]=cy-hs; ax1[a]=cx+hs; ay1[a]=cy+hs;
    areaA[a]=(ax1[a]-ax0[a])*(ay1[a]-ay0[a]);
  }
  float bi[3]={-1.f,-1.f,-1.f}, bu[3]={1.f,1.f,1.f};
  int bm[3]={0,0,0};
  #pragma unroll
  for (int m=0;m<MNUM;m++){
    const float bcx=sbox[4*m], bcy=sbox[4*m+1], bw=sbox[4*m+2], bh=sbox[4*m+3];
    const float bx0=bcx-bw*0.5f, by0=bcy-bh*0.5f, bx1=bcx+bw*0.5f, by1=bcy+bh*0.5f;
    const float areaB=(bx1-bx0)*(by1-by0);
    #pragma unroll
    for (int a=0;a<3;a++){
      float iw=fminf(ax1[a],bx1)-fmaxf(ax0[a],bx0);
      float ih=fminf(ay1[a],by1)-fmaxf(ay0[a],by0);
      iw=fmaxf(iw,0.f); ih=fmaxf(ih,0.f);
      const float inter=iw*ih;
      const float uni=areaA[a]+areaB-inter+1e-9f;
      // iou_new > iou_best  <=>  inter*bu > bi*uni   (uni,bu > 0)
      if (inter*bu[a] > bi[a]*uni){ bi[a]=inter; bu[a]=uni; bm[a]=m; }
    }
  }
  #pragma unroll
  for (int a=0;a<3;a++){
    const float best = bi[a]/bu[a];       // same operands as reference iou
    const bool pos = best >= 0.5f;
    const bool neg = best < 0.4f;
    const float o = obj[a];
    const float sp = log1pf(expf(-fabsf(o)));
    const float obj_all = fmaxf(o,0.f) - (pos? o:0.f) + sp;
    if (valid){
      negvals[segbase + (size_t)b*N + pp*3 + a] = neg ? obj_all : -1.f;
      if (neg){
        atomicAdd(&lh[__float_as_uint(obj_all)>>20], 1);
        f[1] += 1.f;
      }
      if (pos){
        f[0]+=1.f; f[2]+=obj_all;
        const int midx=bm[a];
        int ct = slab[midx]-1; ct = ct<0?0:(ct>CNUM-1?CNUM-1:ct);
        const int cb=a*8;
        float c0=pb[(cb+5)*HW+pp], c1=pb[(cb+6)*HW+pp], c2=pb[(cb+7)*HW+pp];
        float mx=fmaxf(c0,fmaxf(c1,c2));
        float lse=mx+logf(expf(c0-mx)+expf(c1-mx)+expf(c2-mx));
        float csel=(ct==0)?c0:((ct==1)?c1:c2);
        f[3]+=lse-csel;
        const float sz=(a==0)?0.08f:((a==1)?0.16f:0.28f);
        float mcx=sbox[4*midx],mcy=sbox[4*midx+1],mw=sbox[4*midx+2],mh=sbox[4*midx+3];
        float t0=(mcx-cx)/sz,t1=(mcy-cy)/sz,t2=logf(mw/sz),t3=logf(mh/sz);
        float l0=pb[(cb+0)*HW+pp],l1=pb[(cb+1)*HW+pp],l2=pb[(cb+2)*HW+pp],l3=pb[(cb+3)*HW+pp];
        float ssum=0.f,d;
        d=fabsf(l0-t0); ssum+=(d<1.f)?(0.5f*d*d):(d-0.5f);
        d=fabsf(l1-t1); ssum+=(d<1.f)?(0.5f*d*d):(d-0.5f);
        d=fabsf(l2-t2); ssum+=(d<1.f)?(0.5f*d*d):(d-0.5f);
        d=fabsf(l3-t3); ssum+=(d<1.f)?(0.5f*d*d):(d-0.5f);
        f[4]+=ssum;
      }
    }
  }
}

// Merged over all 3 scales; LDS-private histogram fused; last block per
// segment (relaxed arrival counter) computes the radix pick (T, kk, cab).
__global__ __launch_bounds__(256) void k1_all(
    const float* __restrict__ pred0, const float* __restrict__ pred1,
    const float* __restrict__ pred2, const float* __restrict__ boxes,
    const int* __restrict__ labels, float* __restrict__ negvals)
{
  __shared__ float sbox[MNUM*4];
  __shared__ int   slab[MNUM];
  __shared__ int   lh[NBIN];          // 16 KB (reused as global-hist copy in pick)
  __shared__ float red[5][4];

  const int b = blockIdx.y;
  if (threadIdx.x < MNUM*4) sbox[threadIdx.x] = boxes[b*MNUM*4 + threadIdx.x];
  else if (threadIdx.x < MNUM*5) slab[threadIdx.x - MNUM*4] = labels[b*MNUM + (threadIdx.x - MNUM*4)];
  int4* lh4 = (int4*)lh;
  for (int i=threadIdx.x; i<NBIN/4; i+=256) lh4[i] = make_int4(0,0,0,0);
  __syncthreads();

  const int c = blockIdx.x;   // 0..131 : 100 s0 + 25 s1 + 7 s2
  float f[5] = {0.f,0.f,0.f,0.f,0.f};
  int g, nblk;
  if (c < 100){ g = b; nblk = 100;
    k1_work<160,160,0>(pred0, negvals, sbox, slab, b, c*256 + (int)threadIdx.x, lh, f); }
  else if (c < 125){ g = BNUM + b; nblk = 25;
    k1_work<80,80,1>(pred1, negvals, sbox, slab, b, (c-100)*256 + (int)threadIdx.x, lh, f); }
  else { g = 2*BNUM + b; nblk = 7;
    k1_work<40,40,2>(pred2, negvals, sbox, slab, b, (c-125)*256 + (int)threadIdx.x, lh, f); }

  const int lane = threadIdx.x & 63, wv = threadIdx.x >> 6;
  #pragma unroll
  for (int q=0;q<5;q++){
    float r = wred(f[q]);
    if (lane==0) red[q][wv] = r;
  }
  __syncthreads();
  if (threadIdx.x < 5){
    const int q = threadIdx.x;
    float t = red[q][0]+red[q][1]+red[q][2]+red[q][3];
    if (t != 0.f) atomicAdd(&g_acc[g*5+q], t);
  }
  int* gh = g_hist + (size_t)g*NBIN;
  for (int i=threadIdx.x; i<NBIN/4; i+=256){
    int4 hv = lh4[i];
    if (hv.x) atomicAdd(gh + i*4 + 0, hv.x);
    if (hv.y) atomicAdd(gh + i*4 + 1, hv.y);
    if (hv.z) atomicAdd(gh + i*4 + 2, hv.z);
    if (hv.w) atomicAdd(gh + i*4 + 3, hv.w);
  }
  __syncthreads();   // drains vmcnt -> all flush atomics acked

  // ---- relaxed arrival; last block per segment runs the pick ----
  __shared__ int s_lastb;
  if (threadIdx.x==0) s_lastb = (arrive(&g_arr1[g]) == nblk-1) ? 1 : 0;
  __syncthreads();
  if (!s_lastb) return;

  // Reload full per-segment hist (agent-scope loads bypass local L2).
  for (int i=threadIdx.x; i<NBIN; i+=256) lh[i] = aload_i(gh + i);
  __shared__ float s_np, s_av;
  if (threadIdx.x==0){
    s_np = aload_f(&g_acc[g*5+0]);
    s_av = aload_f(&g_acc[g*5+1]);
  }
  __syncthreads();

  const int npos = (int)(s_np + 0.5f);
  const int avail = (int)(s_av + 0.5f);
  const int k = (npos==0) ? (avail < 100 ? avail : 100)
                          : (3*npos < avail ? 3*npos : avail);

  __shared__ int tsum[256];
  __shared__ int s_tt, s_cum;
  int ssum2 = 0;
  #pragma unroll
  for (int i=0;i<16;i++) ssum2 += lh[threadIdx.x*16 + i];
  tsum[threadIdx.x] = ssum2;
  __syncthreads();

  if (k > 0){
    if (threadIdx.x==0){
      int cum=0, tt=0;
      for (int t=255;t>=0;t--){
        if (cum + tsum[t] >= k){ tt=t; break; }
        cum += tsum[t];
      }
      s_tt = tt; s_cum = cum;
    }
    __syncthreads();
    if (threadIdx.x == s_tt){
      int cum = s_cum, T=0, kk=0;
      for (int j=15;j>=0;j--){
        int cc = lh[s_tt*16 + j];
        if (cum + cc >= k){ T = s_tt*16 + j; kk = k - cum; break; }
        cum += cc;
      }
      g_T[g]=T; g_kk[g]=kk; g_cab[g]=cum;
    }
  } else if (threadIdx.x==0){
    g_T[g]=0x7FFFFFFF; g_kk[g]=0; g_cab[g]=0;
  }
}

// Full-width scan (sum above-bin, compact in-bin candidates) fused with the
// per-segment refinement; self-cleans all state for the next iteration.
__global__ __launch_bounds__(256) void k2_scanfin(
    const float* __restrict__ negvals, float* __restrict__ out)
{
  const int bid = blockIdx.x;            // 672 blocks
  const int b = bid / CPB;
  int s, ci; seg_map(bid % CPB, s, ci);
  const int g = s*BNUM + b;
  int N; size_t segbase; seg_geom(s, N, segbase);
  const float* segc = negvals + segbase + (size_t)b*N + (size_t)ci*CHUNK;
  const int T = g_T[g];
  const int lane = threadIdx.x & 63;
  const int nblk = (s==0) ? 16 : ((s==1) ? 4 : 1);

  __shared__ float cv[CAP];              // 32 KB (fin phase)
  __shared__ int hist[256];
  __shared__ int s_bin, s_rem, s_lastb;
  __shared__ float redf[4];
  __shared__ int   redi[4];
  __shared__ int   s_base, s_loc;
  __shared__ float red2[2][4];

  const float4* p4 = (const float4*)segc;
  float sab = 0.f; int cnt = 0;

  // Pass A: count in-bin, sum above-bin.
  for (int i = threadIdx.x; i < CHUNK/4; i += 256){
    float4 v4 = p4[i];
    #pragma unroll
    for (int j=0;j<4;j++){
      float v = (&v4.x)[j];
      if (v < 0.f) continue;
      const int bin = (int)(__float_as_uint(v) >> 20);
      if (bin > T) sab += v;
      else if (bin == T) cnt++;
    }
  }

  float r = wred(sab); int c2 = wredi(cnt);
  if (lane == 0){ redf[threadIdx.x>>6] = r; redi[threadIdx.x>>6] = c2; }
  __syncthreads();
  if (threadIdx.x == 0){
    float t = redf[0]+redf[1]+redf[2]+redf[3];
    int   n = redi[0]+redi[1]+redi[2]+redi[3];
    if (t != 0.f) atomicAdd(&g_sab[g], t);
    s_base = (n > 0) ? atomicAdd(&g_ccnt[g], n) : 0;
    s_loc = 0;
  }
  __syncthreads();
  const int base = s_base;
  const bool anyT = (__syncthreads_count(cnt > 0) != 0);

  // Pass B: compact in-bin values (chunk is cache-hot; order irrelevant).
  if (anyT){
    for (int i = threadIdx.x; i < CHUNK/4; i += 256){
      float4 v4 = p4[i];
      #pragma unroll
      for (int j=0;j<4;j++){
        float v = (&v4.x)[j];
        const bool isT = (v >= 0.f) && ((int)(__float_as_uint(v) >> 20) == T);
        unsigned long long peers = __ballot(isT ? 1 : 0);
        if (isT){
          const int leader = __ffsll(peers) - 1;
          int wbase = 0;
          if (lane == leader) wbase = atomicAdd(&s_loc, (int)__popcll(peers));
          wbase = __shfl(wbase, leader, 64);
          const int idx = base + wbase + (int)__popcll(peers & ((1ull<<lane)-1ull));
          if (idx < CAP)
            __hip_atomic_store(&g_cand[(size_t)g*CAP + idx], v,
                               __ATOMIC_RELAXED, __HIP_MEMORY_SCOPE_AGENT);
        }
      }
    }
  }
  __syncthreads();   // drains vmcnt -> all stores/atomics acked

  // ---- relaxed arrival; last block per segment runs refinement + loss ----
  if (threadIdx.x==0) s_lastb = (arrive(&g_arr2[g]) == nblk-1) ? 1 : 0;
  __syncthreads();
  if (!s_lastb) return;

  const float* seg = negvals + segbase + (size_t)b*N;   // full segment
  __shared__ float s_np, s_av, s_sab;
  __shared__ int s_C;
  if (threadIdx.x==0){
    s_np  = aload_f(&g_acc[g*5+0]);
    s_av  = aload_f(&g_acc[g*5+1]);
    s_sab = aload_f(&g_sab[g]);
    s_C   = aload_i(&g_ccnt[g]);
  }
  __syncthreads();

  const float npos_f = s_np;
  const int npos = (int)(npos_f + 0.5f);
  const int avail = (int)(s_av + 0.5f);
  const int k = (npos==0) ? (avail < 100 ? avail : 100)
                          : (3*npos < avail ? 3*npos : avail);

  float ss = 0.f, ns = 0.f;
  float sab2 = 0.f, cab_f = 0.f;

  if (k > 0){
    const int kk0 = g_kk[g];
    const int cab = g_cab[g];
    sab2 = s_sab;
    cab_f = (float)cab;
    const int C = s_C;

    unsigned prel = 0, pm = 0;
    int rem = kk0;

    if (C <= CAP){
      for (int i=threadIdx.x; i<C; i+=256)
        cv[i] = aload_f(&g_cand[(size_t)g*CAP + i]);
      __syncthreads();
      #pragma unroll
      for (int p=0;p<3;p++){
        const int shift = (p==0)?12:((p==1)?4:0);
        const unsigned bmax = (p==2)?15u:255u;
        hist[threadIdx.x] = 0;
        __syncthreads();
        for (int i=threadIdx.x; i<C; i+=256){
          unsigned u20 = __float_as_uint(cv[i]) & 0xFFFFFu;
          if ((u20 & pm) == prel) atomicAdd(&hist[(u20>>shift)&bmax], 1);
        }
        __syncthreads();
        if (threadIdx.x==0){
          int cum=0;
          for (int j=(int)bmax;j>=0;j--){
            cum += hist[j];
            if (cum >= rem){ s_bin=j; s_rem = rem-(cum-hist[j]); break; }
          }
        }
        __syncthreads();
        prel |= ((unsigned)s_bin << shift);
        pm |= (bmax << shift);
        rem = s_rem;
        __syncthreads();
      }
      const float thr = __uint_as_float(((unsigned)T << 20) | prel);
      for (int i=threadIdx.x; i<C; i+=256){
        float v = cv[i];
        if (v >= thr){ ss += v; ns += 1.f; }
      }
    } else {
      // Overflow fallback: radix over the full segment from global.
      const float4* q4 = (const float4*)seg;
      const int N4 = N >> 2;
      #pragma unroll
      for (int p=0;p<3;p++){
        const int shift = (p==0)?12:((p==1)?4:0);
        const unsigned bmax = (p==2)?15u:255u;
        hist[threadIdx.x] = 0;
        __syncthreads();
        for (int i=threadIdx.x; i<N4; i+=256){
          float4 v4 = q4[i];
          #pragma unroll
          for (int j=0;j<4;j++){
            float v = (&v4.x)[j];
            if (v < 0.f) continue;
            unsigned u = __float_as_uint(v);
            if ((int)(u >> 20) != T) continue;
            unsigned u20 = u & 0xFFFFFu;
            if ((u20 & pm) == prel) atomicAdd(&hist[(u20>>shift)&bmax], 1);
          }
        }
        __syncthreads();
        if (threadIdx.x==0){
          int cum=0;
          for (int j=(int)bmax;j>=0;j--){
            cum += hist[j];
            if (cum >= rem){ s_bin=j; s_rem = rem-(cum-hist[j]); break; }
          }
        }
        __syncthreads();
        prel |= ((unsigned)s_bin << shift);
        pm |= (bmax << shift);
        rem = s_rem;
        __syncthreads();
      }
      const float thr = __uint_as_float(((unsigned)T << 20) | prel);
      for (int i=threadIdx.x; i<N4; i+=256){
        float4 v4 = q4[i];
        #pragma unroll
        for (int j=0;j<4;j++){
          float v = (&v4.x)[j];
          if (v < 0.f) continue;
          if ((int)(__float_as_uint(v) >> 20) == T && v >= thr){ ss += v; ns += 1.f; }
        }
      }
    }
  }

  const int wv = threadIdx.x >> 6;
  float r0 = wred(ss), r1 = wred(ns);
  if (lane==0){ red2[0][wv]=r0; red2[1][wv]=r1; }
  __syncthreads();
  if (threadIdx.x==0){
    float sstot = sab2 + red2[0][0]+red2[0][1]+red2[0][2]+red2[0][3];
    float nstot = cab_f + red2[1][0]+red2[1][1]+red2[1][2]+red2[1][3];
    float cnt2 = npos_f + nstot;
    float ag2 = aload_f(&g_acc[g*5+2]);
    float ag3 = aload_f(&g_acc[g*5+3]);
    float ag4 = aload_f(&g_acc[g*5+4]);
    float lo = (cnt2 > 0.f) ? (ag2 + sstot)/cnt2 : 0.f;
    float lc = (npos > 0) ? ag3/npos_f : 0.f;
    float ll = (npos > 0) ? ag4/(npos_f*4.f) : 0.f;
    atomicAdd(&g_lsum[0], lo);
    atomicAdd(&g_lsum[1], lc);
    atomicAdd(&g_lsum[2], ll);
    // lsum adds acked, then relaxed done-increment; last reads via agent loads
    if (arrive(&g_done) == NSEG-1){
      float L0 = aload_f(&g_lsum[0]);
      float L1 = aload_f(&g_lsum[1]);
      float L2 = aload_f(&g_lsum[2]);
      float lo2 = L0*(1.f/32.f), lc2 = L1*(1.f/32.f), ll2 = L2*(1.f/32.f);
      out[0]=lo2; out[1]=lc2; out[2]=ll2; out[3]=lo2+lc2+ll2;
      // reset global scalars for the next iteration (end-of-kernel flush
      // makes these visible to the next launch in stream order)
      g_lsum[0]=0.f; g_lsum[1]=0.f; g_lsum[2]=0.f; g_done=0;
    }
  }

  // ---- self-clean this segment's state for the next iteration ----
  __syncthreads();
  int* gh = g_hist + (size_t)g*NBIN;
  int4* gh4 = (int4*)gh;
  for (int i=threadIdx.x; i<NBIN/4; i+=256) gh4[i] = make_int4(0,0,0,0);
  if (threadIdx.x < 5) g_acc[g*5 + threadIdx.x] = 0.f;
  if (threadIdx.x == 5) g_sab[g] = 0.f;
  if (threadIdx.x == 6) g_ccnt[g] = 0;
  if (threadIdx.x == 7) g_arr1[g] = 0;
  if (threadIdx.x == 8) g_arr2[g] = 0;
}

extern "C" void kernel_launch(void* const* d_in, const int* in_sizes, int n_in,
                              void* d_out, int out_size, void* d_ws, size_t ws_size,
                              hipStream_t stream)
{
  const float* pred0 = (const float*)d_in[0];
  const float* pred1 = (const float*)d_in[1];
  const float* pred2 = (const float*)d_in[2];
  const float* boxes = (const float*)d_in[6];
  const int*   labels = (const int*)d_in[7];
  float* out = (float*)d_out;

  float* negvals = (float*)d_ws;   // 3,225,600 floats = 12.9 MB (only ws use)

  k1_all<<<dim3(132,32), 256, 0, stream>>>(pred0, pred1, pred2, boxes, labels, negvals);
  k2_scanfin<<<672, 256, 0, stream>>>(negvals, out);
}

// Round 9
// 220.497 us; speedup vs baseline: 1.7119x; 1.0920x over previous
//
#include <hip/hip_runtime.h>
#include <math.h>

#define ANUM 3
#define CNUM 3
#define BNUM 32
#define MNUM 16
#define CH 24      // ANUM*(5+CNUM)
#define NBIN 4096  // 12-bit float-top-bits histogram (sign=0 for all values)
#define NSEG 96
#define CAP 8192   // max in-threshold-bin candidates kept
#define BCAP 1024  // per-block LDS candidate buffer
#define CHUNK 4800 // elements per chunk; divides 76800/19200/4800
#define CPB 21     // chunks per batch image: 16 + 4 + 1

// All small state in static device memory (zero-initialized at load).
// Each iteration self-cleans -> no init kernel needed.
__device__ __align__(16) int   g_hist[NSEG*NBIN];
__device__ __align__(16) float g_cand[(size_t)NSEG*CAP];
__device__ int   g_ccnt[NSEG];
__device__ int   g_T[NSEG];
__device__ int   g_kk[NSEG];
__device__ int   g_cab[NSEG];   // count strictly above bin T
__device__ float g_sab[NSEG];   // sum of values strictly above bin T
__device__ float g_acc[NSEG*5];
__device__ float g_lsum[3];
__device__ int   g_arr1[NSEG];  // k1 per-segment arrival
__device__ int   g_arr2[NSEG];  // scan per-segment arrival
__device__ int   g_done;

__device__ __forceinline__ float wred(float v){
  #pragma unroll
  for (int off=32; off; off>>=1) v += __shfl_down(v, off, 64);
  return v;
}

// Relaxed agent-scope arrival. Prior VMEM ops of this wave are drained via
// explicit vmcnt(0); relaxed RMW adds NO L2 writeback/invalidate
// (acq_rel cost ~4000 wbl2+inv ops = 3.5x slowdown, r7 measured).
__device__ __forceinline__ int arrive(int* ctr){
  asm volatile("s_waitcnt vmcnt(0)" ::: "memory");
  return __hip_atomic_fetch_add(ctr, 1, __ATOMIC_RELAXED, __HIP_MEMORY_SCOPE_AGENT);
}
__device__ __forceinline__ int aload_i(const int* p){
  return __hip_atomic_load(p, __ATOMIC_RELAXED, __HIP_MEMORY_SCOPE_AGENT);
}
__device__ __forceinline__ float aload_f(const float* p){
  return __hip_atomic_load(p, __ATOMIC_RELAXED, __HIP_MEMORY_SCOPE_AGENT);
}
__device__ __forceinline__ void astore_f(float* p, float v){
  __hip_atomic_store(p, v, __ATOMIC_RELAXED, __HIP_MEMORY_SCOPE_AGENT);
}

__device__ __forceinline__ void seg_map(int c, int& s, int& ci){
  if (c < 16){ s = 0; ci = c; }
  else if (c < 20){ s = 1; ci = c - 16; }
  else { s = 2; ci = 0; }
}
__device__ __forceinline__ void seg_geom(int s, int& N, size_t& segbase){
  N = (s==0) ? 76800 : ((s==1) ? 19200 : 4800);
  segbase = (s==0) ? 0
          : ((s==1) ? (size_t)BNUM*76800
                    : (size_t)BNUM*(76800+19200));
}

// One thread per PIXEL: 3 anchors in registers, shared box corners,
// conservative big-anchor overlap prune (exact skip: monotone min/max forms
// guarantee original iw<=0 for all anchors), divide-free argmax, one divide
// per anchor at end (same operands/order as reference).
template<int H, int W, int SCALE>
__device__ __forceinline__ void k1_work(
    const float* __restrict__ pred, float* __restrict__ negvals,
    const float* sbox, const int* slab, int b, int pix, int* lh, float* f)
{
  constexpr int HW = H*W;
  constexpr int N = HW*ANUM;
  constexpr size_t segbase = (SCALE==0) ? 0
                           : ((SCALE==1) ? (size_t)BNUM*76800
                                         : (size_t)BNUM*(76800+19200));
  const bool valid = (pix < HW);
  const int pp = valid ? pix : 0;
  const int h = pp / W, w = pp % W;
  const float cx = ((float)w + 0.5f)/(float)W;
  const float cy = ((float)h + 0.5f)/(float)H;

  const float* pb = pred + (size_t)b*CH*HW;
  float obj[3];
  #pragma unroll
  for (int a=0;a<3;a++) obj[a] = pb[(a*8+4)*HW + pp];   // coalesced

  float ax0[3],ay0[3],ax1[3],ay1[3],areaA[3];
  #pragma unroll
  for (int a=0;a<3;a++){
    const float sz=(a==0)?0.08f:((a==1)?0.16f:0.28f);
    const float hs=sz*0.5f;
    ax0[a]=cx-hs; ay0[a]=cy-hs; ax1[a]=cx+hs; ay1[a]=cy+hs;
    areaA[a]=(ax1[a]-ax0[a])*(ay1[a]-ay0[a]);
  }
  // big-anchor footprint (hs_max = 0.14) for the conservative prune
  const float axr = cx + 0.14f, axl = cx - 0.14f;
  const float ayr = cy + 0.14f, ayl = cy - 0.14f;

  float bi[3]={-1.f,-1.f,-1.f}, bu[3]={1.f,1.f,1.f};
  int bm[3]={0,0,0};
  #pragma unroll 4
  for (int m=0;m<MNUM;m++){
    const float bcx=sbox[4*m], bcy=sbox[4*m+1], bw=sbox[4*m+2], bh=sbox[4*m+3];
    const float bx0=bcx-bw*0.5f, by0=bcy-bh*0.5f, bx1=bcx+bw*0.5f, by1=bcy+bh*0.5f;
    // prune: if the LARGEST anchor has no overlap, every anchor's original
    // iw/ih <= 0 (monotone in hs) -> inter = 0 exactly -> no update needed.
    const float iwb = fminf(axr,bx1) - fmaxf(axl,bx0);
    const float ihb = fminf(ayr,by1) - fmaxf(ayl,by0);
    if (iwb <= 0.f || ihb <= 0.f) continue;
    const float areaB=(bx1-bx0)*(by1-by0);
    #pragma unroll
    for (int a=0;a<3;a++){
      float iw=fminf(ax1[a],bx1)-fmaxf(ax0[a],bx0);
      float ih=fminf(ay1[a],by1)-fmaxf(ay0[a],by0);
      iw=fmaxf(iw,0.f); ih=fmaxf(ih,0.f);
      const float inter=iw*ih;
      const float uni=areaA[a]+areaB-inter+1e-9f;
      // iou_new > iou_best  <=>  inter*bu > bi*uni   (uni,bu > 0)
      if (inter*bu[a] > bi[a]*uni){ bi[a]=inter; bu[a]=uni; bm[a]=m; }
    }
  }
  #pragma unroll
  for (int a=0;a<3;a++){
    const float best = bi[a]/bu[a];       // same operands as reference iou
    const bool pos = best >= 0.5f;
    const bool neg = best < 0.4f;
    const float o = obj[a];
    const float sp = log1pf(expf(-fabsf(o)));
    const float obj_all = fmaxf(o,0.f) - (pos? o:0.f) + sp;
    if (valid){
      negvals[segbase + (size_t)b*N + pp*3 + a] = neg ? obj_all : -1.f;
      if (neg){
        atomicAdd(&lh[__float_as_uint(obj_all)>>20], 1);
        f[1] += 1.f;
      }
      if (pos){
        f[0]+=1.f; f[2]+=obj_all;
        const int midx=bm[a];
        int ct = slab[midx]-1; ct = ct<0?0:(ct>CNUM-1?CNUM-1:ct);
        const int cb=a*8;
        float c0=pb[(cb+5)*HW+pp], c1=pb[(cb+6)*HW+pp], c2=pb[(cb+7)*HW+pp];
        float mx=fmaxf(c0,fmaxf(c1,c2));
        float lse=mx+logf(expf(c0-mx)+expf(c1-mx)+expf(c2-mx));
        float csel=(ct==0)?c0:((ct==1)?c1:c2);
        f[3]+=lse-csel;
        const float sz=(a==0)?0.08f:((a==1)?0.16f:0.28f);
        float mcx=sbox[4*midx],mcy=sbox[4*midx+1],mw=sbox[4*midx+2],mh=sbox[4*midx+3];
        float t0=(mcx-cx)/sz,t1=(mcy-cy)/sz,t2=logf(mw/sz),t3=logf(mh/sz);
        float l0=pb[(cb+0)*HW+pp],l1=pb[(cb+1)*HW+pp],l2=pb[(cb+2)*HW+pp],l3=pb[(cb+3)*HW+pp];
        float ssum=0.f,d;
        d=fabsf(l0-t0); ssum+=(d<1.f)?(0.5f*d*d):(d-0.5f);
        d=fabsf(l1-t1); ssum+=(d<1.f)?(0.5f*d*d):(d-0.5f);
        d=fabsf(l2-t2); ssum+=(d<1.f)?(0.5f*d*d):(d-0.5f);
        d=fabsf(l3-t3); ssum+=(d<1.f)?(0.5f*d*d):(d-0.5f);
        f[4]+=ssum;
      }
    }
  }
}

// Merged over all 3 scales; LDS-private histogram fused; last block per
// segment (relaxed arrival counter) computes the radix pick (T, kk, cab).
__global__ __launch_bounds__(256) void k1_all(
    const float* __restrict__ pred0, const float* __restrict__ pred1,
    const float* __restrict__ pred2, const float* __restrict__ boxes,
    const int* __restrict__ labels, float* __restrict__ negvals)
{
  __shared__ float sbox[MNUM*4];
  __shared__ int   slab[MNUM];
  __shared__ int   lh[NBIN];          // 16 KB (reused as global-hist copy in pick)
  __shared__ float red[5][4];

  const int b = blockIdx.y;
  if (threadIdx.x < MNUM*4) sbox[threadIdx.x] = boxes[b*MNUM*4 + threadIdx.x];
  else if (threadIdx.x < MNUM*5) slab[threadIdx.x - MNUM*4] = labels[b*MNUM + (threadIdx.x - MNUM*4)];
  int4* lh4 = (int4*)lh;
  for (int i=threadIdx.x; i<NBIN/4; i+=256) lh4[i] = make_int4(0,0,0,0);
  __syncthreads();

  const int c = blockIdx.x;   // 0..131 : 100 s0 + 25 s1 + 7 s2
  float f[5] = {0.f,0.f,0.f,0.f,0.f};
  int g, nblk;
  if (c < 100){ g = b; nblk = 100;
    k1_work<160,160,0>(pred0, negvals, sbox, slab, b, c*256 + (int)threadIdx.x, lh, f); }
  else if (c < 125){ g = BNUM + b; nblk = 25;
    k1_work<80,80,1>(pred1, negvals, sbox, slab, b, (c-100)*256 + (int)threadIdx.x, lh, f); }
  else { g = 2*BNUM + b; nblk = 7;
    k1_work<40,40,2>(pred2, negvals, sbox, slab, b, (c-125)*256 + (int)threadIdx.x, lh, f); }

  const int lane = threadIdx.x & 63, wv = threadIdx.x >> 6;
  #pragma unroll
  for (int q=0;q<5;q++){
    float r = wred(f[q]);
    if (lane==0) red[q][wv] = r;
  }
  __syncthreads();
  if (threadIdx.x < 5){
    const int q = threadIdx.x;
    float t = red[q][0]+red[q][1]+red[q][2]+red[q][3];
    if (t != 0.f) atomicAdd(&g_acc[g*5+q], t);
  }
  int* gh = g_hist + (size_t)g*NBIN;
  for (int i=threadIdx.x; i<NBIN/4; i+=256){
    int4 hv = lh4[i];
    if (hv.x) atomicAdd(gh + i*4 + 0, hv.x);
    if (hv.y) atomicAdd(gh + i*4 + 1, hv.y);
    if (hv.z) atomicAdd(gh + i*4 + 2, hv.z);
    if (hv.w) atomicAdd(gh + i*4 + 3, hv.w);
  }
  __syncthreads();

  // ---- relaxed arrival; last block per segment runs the pick ----
  __shared__ int s_lastb;
  if (threadIdx.x==0) s_lastb = (arrive(&g_arr1[g]) == nblk-1) ? 1 : 0;
  __syncthreads();
  if (!s_lastb) return;

  // Reload full per-segment hist (agent-scope loads see all blocks' adds).
  for (int i=threadIdx.x; i<NBIN; i+=256) lh[i] = aload_i(gh + i);
  __shared__ float s_np, s_av;
  if (threadIdx.x==0){
    s_np = aload_f(&g_acc[g*5+0]);
    s_av = aload_f(&g_acc[g*5+1]);
  }
  __syncthreads();

  const int npos = (int)(s_np + 0.5f);
  const int avail = (int)(s_av + 0.5f);
  const int k = (npos==0) ? (avail < 100 ? avail : 100)
                          : (3*npos < avail ? 3*npos : avail);

  __shared__ int tsum[256];
  __shared__ int s_tt, s_cum;
  int ssum2 = 0;
  #pragma unroll
  for (int i=0;i<16;i++) ssum2 += lh[threadIdx.x*16 + i];
  tsum[threadIdx.x] = ssum2;
  __syncthreads();

  if (k > 0){
    if (threadIdx.x==0){
      int cum=0, tt=0;
      for (int t=255;t>=0;t--){
        if (cum + tsum[t] >= k){ tt=t; break; }
        cum += tsum[t];
      }
      s_tt = tt; s_cum = cum;
    }
    __syncthreads();
    if (threadIdx.x == s_tt){
      int cum = s_cum, T=0, kk=0;
      for (int j=15;j>=0;j--){
        int cc = lh[s_tt*16 + j];
        if (cum + cc >= k){ T = s_tt*16 + j; kk = k - cum; break; }
        cum += cc;
      }
      g_T[g]=T; g_kk[g]=kk; g_cab[g]=cum;
    }
  } else if (threadIdx.x==0){
    g_T[g]=0x7FFFFFFF; g_kk[g]=0; g_cab[g]=0;
  }
}

// Single streaming pass: sum above-bin values, compact rare in-bin hits via
// a small LDS buffer (one LDS atomic per hit, one global reservation per
// block). Last block per segment runs the radix refinement + loss; self-
// cleans all state for the next iteration.
__global__ __launch_bounds__(256) void k2_scanfin(
    const float* __restrict__ negvals, float* __restrict__ out)
{
  const int bid = blockIdx.x;            // 672 blocks
  const int b = bid / CPB;
  int s, ci; seg_map(bid % CPB, s, ci);
  const int g = s*BNUM + b;
  int N; size_t segbase; seg_geom(s, N, segbase);
  const float* segc = negvals + segbase + (size_t)b*N + (size_t)ci*CHUNK;
  const int T = g_T[g];
  const int lane = threadIdx.x & 63;
  const int nblk = (s==0) ? 16 : ((s==1) ? 4 : 1);

  __shared__ float slv[BCAP];            // 4 KB in-bin collection buffer
  __shared__ float cv[CAP];              // 32 KB (fin phase)
  __shared__ int hist[256];
  __shared__ int s_bin, s_rem, s_lastb;
  __shared__ float redf[4];
  __shared__ int   s_base, s_loc, s_loc2;
  __shared__ float red2[2][4];

  if (threadIdx.x==0){ s_loc = 0; s_loc2 = 0; }
  __syncthreads();

  const float4* p4 = (const float4*)segc;
  float sab = 0.f;

  // One pass: above-bin sum + in-bin collection (hits are rare).
  for (int i = threadIdx.x; i < CHUNK/4; i += 256){
    float4 v4 = p4[i];
    #pragma unroll
    for (int j=0;j<4;j++){
      float v = (&v4.x)[j];
      if (v < 0.f) continue;
      const int bin = (int)(__float_as_uint(v) >> 20);
      if (bin > T) sab += v;
      else if (bin == T){
        int idx = atomicAdd(&s_loc, 1);
        if (idx < BCAP) slv[idx] = v;
      }
    }
  }

  float r = wred(sab);
  if (lane == 0) redf[threadIdx.x>>6] = r;
  __syncthreads();
  const int n = s_loc;
  if (threadIdx.x == 0){
    float t = redf[0]+redf[1]+redf[2]+redf[3];
    if (t != 0.f) atomicAdd(&g_sab[g], t);
    s_base = (n > 0) ? atomicAdd(&g_ccnt[g], n) : 0;
  }
  __syncthreads();
  const int base = s_base;

  // Copy collected candidates out (order irrelevant: multiset).
  const int ncap = (n < BCAP) ? n : BCAP;
  for (int i = threadIdx.x; i < ncap; i += 256){
    const int idx = base + i;
    if (idx < CAP) astore_f(&g_cand[(size_t)g*CAP + idx], slv[i]);
  }
  if (n > BCAP){
    // rare overflow: exact rescan, direct-store the remainder
    for (int i = threadIdx.x; i < CHUNK/4; i += 256){
      float4 v4 = p4[i];
      #pragma unroll
      for (int j=0;j<4;j++){
        float v = (&v4.x)[j];
        if (v < 0.f) continue;
        if ((int)(__float_as_uint(v) >> 20) == T){
          int idx2 = atomicAdd(&s_loc2, 1);
          if (idx2 >= BCAP && base + idx2 < CAP)
            astore_f(&g_cand[(size_t)g*CAP + base + idx2], v);
        }
      }
    }
  }
  __syncthreads();

  // ---- relaxed arrival; last block per segment runs refinement + loss ----
  if (threadIdx.x==0) s_lastb = (arrive(&g_arr2[g]) == nblk-1) ? 1 : 0;
  __syncthreads();
  if (!s_lastb) return;

  const float* seg = negvals + segbase + (size_t)b*N;   // full segment
  __shared__ float s_np, s_av, s_sab;
  __shared__ int s_C;
  if (threadIdx.x==0){
    s_np  = aload_f(&g_acc[g*5+0]);
    s_av  = aload_f(&g_acc[g*5+1]);
    s_sab = aload_f(&g_sab[g]);
    s_C   = aload_i(&g_ccnt[g]);
  }
  __syncthreads();

  const float npos_f = s_np;
  const int npos = (int)(npos_f + 0.5f);
  const int avail = (int)(s_av + 0.5f);
  const int k = (npos==0) ? (avail < 100 ? avail : 100)
                          : (3*npos < avail ? 3*npos : avail);

  float ss = 0.f, ns = 0.f;
  float sab2 = 0.f, cab_f = 0.f;

  if (k > 0){
    const int kk0 = g_kk[g];
    const int cab = g_cab[g];
    sab2 = s_sab;
    cab_f = (float)cab;
    const int C = s_C;

    unsigned prel = 0, pm = 0;
    int rem = kk0;

    if (C <= CAP){
      for (int i=threadIdx.x; i<C; i+=256)
        cv[i] = aload_f(&g_cand[(size_t)g*CAP + i]);
      __syncthreads();
      #pragma unroll
      for (int p=0;p<3;p++){
        const int shift = (p==0)?12:((p==1)?4:0);
        const unsigned bmax = (p==2)?15u:255u;
        hist[threadIdx.x] = 0;
        __syncthreads();
        for (int i=threadIdx.x; i<C; i+=256){
          unsigned u20 = __float_as_uint(cv[i]) & 0xFFFFFu;
          if ((u20 & pm) == prel) atomicAdd(&hist[(u20>>shift)&bmax], 1);
        }
        __syncthreads();
        if (threadIdx.x==0){
          int cum=0;
          for (int j=(int)bmax;j>=0;j--){
            cum += hist[j];
            if (cum >= rem){ s_bin=j; s_rem = rem-(cum-hist[j]); break; }
          }
        }
        __syncthreads();
        prel |= ((unsigned)s_bin << shift);
        pm |= (bmax << shift);
        rem = s_rem;
        __syncthreads();
      }
      const float thr = __uint_as_float(((unsigned)T << 20) | prel);
      for (int i=threadIdx.x; i<C; i+=256){
        float v = cv[i];
        if (v >= thr){ ss += v; ns += 1.f; }
      }
    } else {
      // Overflow fallback: radix over the full segment from global.
      const float4* q4 = (const float4*)seg;
      const int N4 = N >> 2;
      #pragma unroll
      for (int p=0;p<3;p++){
        const int shift = (p==0)?12:((p==1)?4:0);
        const unsigned bmax = (p==2)?15u:255u;
        hist[threadIdx.x] = 0;
        __syncthreads();
        for (int i=threadIdx.x; i<N4; i+=256){
          float4 v4 = q4[i];
          #pragma unroll
          for (int j=0;j<4;j++){
            float v = (&v4.x)[j];
            if (v < 0.f) continue;
            unsigned u = __float_as_uint(v);
            if ((int)(u >> 20) != T) continue;
            unsigned u20 = u & 0xFFFFFu;
            if ((u20 & pm) == prel) atomicAdd(&hist[(u20>>shift)&bmax], 1);
          }
        }
        __syncthreads();
        if (threadIdx.x==0){
          int cum=0;
          for (int j=(int)bmax;j>=0;j--){
            cum += hist[j];
            if (cum >= rem){ s_bin=j; s_rem = rem-(cum-hist[j]); break; }
          }
        }
        __syncthreads();
        prel |= ((unsigned)s_bin << shift);
        pm |= (bmax << shift);
        rem = s_rem;
        __syncthreads();
      }
      const float thr = __uint_as_float(((unsigned)T << 20) | prel);
      for (int i=threadIdx.x; i<N4; i+=256){
        float4 v4 = q4[i];
        #pragma unroll
        for (int j=0;j<4;j++){
          float v = (&v4.x)[j];
          if (v < 0.f) continue;
          if ((int)(__float_as_uint(v) >> 20) == T && v >= thr){ ss += v; ns += 1.f; }
        }
      }
    }
  }

  const int wv = threadIdx.x >> 6;
  float r0 = wred(ss), r1 = wred(ns);
  if (lane==0){ red2[0][wv]=r0; red2[1][wv]=r1; }
  __syncthreads();
  if (threadIdx.x==0){
    float sstot = sab2 + red2[0][0]+red2[0][1]+red2[0][2]+red2[0][3];
    float nstot = cab_f + red2[1][0]+red2[1][1]+red2[1][2]+red2[1][3];
    float cnt2 = npos_f + nstot;
    float ag2 = aload_f(&g_acc[g*5+2]);
    float ag3 = aload_f(&g_acc[g*5+3]);
    float ag4 = aload_f(&g_acc[g*5+4]);
    float lo = (cnt2 > 0.f) ? (ag2 + sstot)/cnt2 : 0.f;
    float lc = (npos > 0) ? ag3/npos_f : 0.f;
    float ll = (npos > 0) ? ag4/(npos_f*4.f) : 0.f;
    atomicAdd(&g_lsum[0], lo);
    atomicAdd(&g_lsum[1], lc);
    atomicAdd(&g_lsum[2], ll);
    if (arrive(&g_done) == NSEG-1){
      float L0 = aload_f(&g_lsum[0]);
      float L1 = aload_f(&g_lsum[1]);
      float L2 = aload_f(&g_lsum[2]);
      float lo2 = L0*(1.f/32.f), lc2 = L1*(1.f/32.f), ll2 = L2*(1.f/32.f);
      out[0]=lo2; out[1]=lc2; out[2]=ll2; out[3]=lo2+lc2+ll2;
      g_lsum[0]=0.f; g_lsum[1]=0.f; g_lsum[2]=0.f; g_done=0;
    }
  }

  // ---- self-clean this segment's state for the next iteration ----
  __syncthreads();
  int* gh = g_hist + (size_t)g*NBIN;
  int4* gh4 = (int4*)gh;
  for (int i=threadIdx.x; i<NBIN/4; i+=256) gh4[i] = make_int4(0,0,0,0);
  if (threadIdx.x < 5) g_acc[g*5 + threadIdx.x] = 0.f;
  if (threadIdx.x == 5) g_sab[g] = 0.f;
  if (threadIdx.x == 6) g_ccnt[g] = 0;
  if (threadIdx.x == 7) g_arr1[g] = 0;
  if (threadIdx.x == 8) g_arr2[g] = 0;
}

extern "C" void kernel_launch(void* const* d_in, const int* in_sizes, int n_in,
                              void* d_out, int out_size, void* d_ws, size_t ws_size,
                              hipStream_t stream)
{
  const float* pred0 = (const float*)d_in[0];
  const float* pred1 = (const float*)d_in[1];
  const float* pred2 = (const float*)d_in[2];
  const float* boxes = (const float*)d_in[6];
  const int*   labels = (const int*)d_in[7];
  float* out = (float*)d_out;

  float* negvals = (float*)d_ws;   // 3,225,600 floats = 12.9 MB (only ws use)

  k1_all<<<dim3(132,32), 256, 0, stream>>>(pred0, pred1, pred2, boxes, labels, negvals);
  k2_scanfin<<<672, 256, 0, stream>>>(negvals, out);
}